// Round 7
// baseline (153.700 us; speedup 1.0000x reference)
//
#include <hip/hip_runtime.h>
#include <hip/hip_bf16.h>
#include <stdint.h>

#define M_DIM 4096
#define N_DIM 4096
#define K_DIM 4096
#define NH 128
#define NW 128
#define NKT 64   // K-tiles of BK=64

typedef short bf16x8 __attribute__((ext_vector_type(8)));
typedef short bf16x4 __attribute__((ext_vector_type(4)));
typedef float f32x4 __attribute__((ext_vector_type(4)));

#define MFMA(a, b, c) __builtin_amdgcn_mfma_f32_16x16x32_bf16((a), (b), (c), 0, 0, 0)

__device__ __forceinline__ short f2bf(float f) {
  union { float f; unsigned u; } c; c.f = f;
  unsigned u = c.u;
  unsigned r = (u + 0x7fffu + ((u >> 16) & 1u)) >> 16;  // RNE
  return (short)r;
}

// ---------------- kernel 1: per-32x32-block mask ----------------
__global__ __launch_bounds__(256) void k_block_mask(const int* __restrict__ mask,
                                                    const float* __restrict__ conv_bias,
                                                    int* __restrict__ bm) {
  const int bw = blockIdx.x, bh = blockIdx.y;
  const int t = threadIdx.x;
  const int row = t >> 3;
  const int c4 = (t & 7) << 2;
  const int4* p = (const int4*)(mask + (size_t)(bh * 32 + row) * K_DIM + bw * 32 + c4);
  int4 v = *p;
  int s = v.x + v.y + v.z + v.w;
#pragma unroll
  for (int off = 32; off > 0; off >>= 1) s += __shfl_down(s, off);
  __shared__ int red[4];
  if ((t & 63) == 0) red[t >> 6] = s;
  __syncthreads();
  if (t == 0) {
    float tot = (float)(red[0] + red[1] + red[2] + red[3]) + conv_bias[0];
    bm[bh * NW + bw] = (tot > 0.0f) ? 1 : 0;
  }
}

// ---------------- kernel 2: data f32 -> bf16 ----------------
__global__ __launch_bounds__(256) void k_cvt_data(const float* __restrict__ in,
                                                  short* __restrict__ ob) {
  size_t i = (size_t)blockIdx.x * 256 + threadIdx.x;
  f32x4 v = ((const f32x4*)in)[i];
  bf16x4 o;
  o[0] = f2bf(v[0]); o[1] = f2bf(v[1]); o[2] = f2bf(v[2]); o[3] = f2bf(v[3]);
  ((bf16x4*)ob)[i] = o;
}

// ---------------- kernel 3: weight f32 -> masked bf16 ----------------
__global__ __launch_bounds__(256) void k_cvt_weight(const float* __restrict__ w,
                                                    const int* __restrict__ bm,
                                                    short* __restrict__ ob) {
  size_t i = (size_t)blockIdx.x * 256 + threadIdx.x;
  int n = (int)(i >> 10);
  int k = ((int)i & 1023) << 2;
  float m = bm[((n >> 5) << 7) + (k >> 5)] ? 1.0f : 0.0f;
  f32x4 v = ((const f32x4*)w)[i];
  bf16x4 o;
  o[0] = f2bf(v[0] * m); o[1] = f2bf(v[1] * m);
  o[2] = f2bf(v[2] * m); o[3] = f2bf(v[3] * m);
  ((bf16x4*)ob)[i] = o;
}

// ---------------- kernel 4: 256x256 pipelined 4-phase bf16 NT GEMM ----------
// Round-6 structure (register pipeline, counted vmcnt, XOR swizzle, XCD
// swizzle, block-sparse MFMA skip) plus BLOCK-SPARSE ds_read SKIP: every
// fragment read serves exactly one mask block whose enable bit is an SGPR;
// guard the reads (wave-uniform branches). Barriers/vmcnts/stages remain
// unconditional -> vmcnt FIFO and LDS liveness identical to round 6.
__global__ __launch_bounds__(512, 2) void k_gemm256(const short* __restrict__ Ab,
                                                    const short* __restrict__ Bb,
                                                    const float* __restrict__ bias,
                                                    const int* __restrict__ bm,
                                                    float* __restrict__ out) {
  __shared__ short Asm[2][2][256][32];  // [buf][ks][row][colseg*8] 64 KB
  __shared__ short Bsm[2][2][256][32];  // 64 KB

  const int tid = threadIdx.x;
  const int wid = tid >> 6, lane = tid & 63;
  const int wr = wid >> 2, wc = wid & 3;
  const int r = lane & 15, g0 = lane >> 4;
  const int gs = g0 ^ ((r >> 1) & 3);      // swizzled col-seg for ds_read

  // XCD-aware swizzle: 256 wgs, 8 XCDs, 32/XCD (bijective since 256%8==0)
  const int swz = (blockIdx.x & 7) * 32 + (blockIdx.x >> 3);
  const int bx = swz & 15, by = swz >> 4;
  const int rowM = by * 256, colN = bx * 256;

  // staging geometry: 512 thr x 16B = one (h,ks) 8KB region, linear LDS dest
  const int srow = tid >> 2;                         // 0..127 within half
  const int sseg = (tid & 3) ^ ((tid >> 3) & 3);     // pre-swizzled source seg
  const int swave = wid * 512;                       // wave-uniform LDS base (shorts)

  const short* gA = Ab + (size_t)(rowM + srow) * K_DIM + sseg * 8;
  const short* gB = Bb + (size_t)(colN + srow) * K_DIM + sseg * 8;
  const size_t HOFF = (size_t)128 * K_DIM;

  // ---- per-wave mask bits: rows nb0, nb0+1 of bm, 128 kc each -> 4x u64 ----
  const int nb0 = (colN >> 5) + wc * 2;
  unsigned long long w00, w01, w10, w11;
  {
    const int* bp = bm + nb0 * NW;
    int v0 = bp[lane], v1 = bp[64 + lane], v2 = bp[128 + lane], v3 = bp[192 + lane];
    w00 = __ballot(v0 != 0); w01 = __ballot(v1 != 0);
    w10 = __ballot(v2 != 0); w11 = __ballot(v3 != 0);
  }
  __builtin_amdgcn_sched_barrier(0);  // mask loads fully retired before staging

#define BT(lo, hi, kc) ((int)((((kc) & 64) ? (hi) : (lo)) >> ((kc) & 63)) & 1)

#define GLL(g, l)                                                            \
  __builtin_amdgcn_global_load_lds((const __attribute__((address_space(1))) void*)(g), \
                                   (__attribute__((address_space(3))) void*)(l), 16, 0, 0)
#define STA(BUF, kt, h, ks) GLL(gA + HOFF * (h) + (size_t)(kt) * 64 + (ks) * 32, \
                                &Asm[BUF][ks][(h) * 128][0] + swave)
#define STB(BUF, kt, h, ks) GLL(gB + HOFF * (h) + (size_t)(kt) * 64 + (ks) * 32, \
                                &Bsm[BUF][ks][(h) * 128][0] + swave)

#define LDA(BUF, ks, m) (*(const bf16x8*)&Asm[BUF][ks][wr * 128 + (m) * 16 + r][gs * 8])
#define LDB(BUF, ks, n) (*(const bf16x8*)&Bsm[BUF][ks][wc * 64 + (n) * 16 + r][gs * 8])

#define MF8(AR, nn, bb)                                                      \
  acc[0][nn] = MFMA(AR[0], bb, acc[0][nn]); acc[1][nn] = MFMA(AR[1], bb, acc[1][nn]); \
  acc[2][nn] = MFMA(AR[2], bb, acc[2][nn]); acc[3][nn] = MFMA(AR[3], bb, acc[3][nn]); \
  acc[4][nn] = MFMA(AR[4], bb, acc[4][nn]); acc[5][nn] = MFMA(AR[5], bb, acc[5][nn]); \
  acc[6][nn] = MFMA(AR[6], bb, acc[6][nn]); acc[7][nn] = MFMA(AR[7], bb, acc[7][nn]);

#define BAR __builtin_amdgcn_s_barrier()
#define SB0 __builtin_amdgcn_sched_barrier(0)
#define PRIO1 __builtin_amdgcn_s_setprio(1)
#define PRIO0 __builtin_amdgcn_s_setprio(0)
#define VMW_(N) asm volatile("s_waitcnt vmcnt(" #N ")" ::: "memory")
#define VMW(N) VMW_(N)

// One K-tile, 4 phases; E0..E3 = activity of the block each phase covers;
// NE0/NE1 = next tile's E0/E1 (guard the cross-tile prefetch).
// Every ds_read is guarded by the bit(s) of the MFMA cluster(s) consuming it.
#define TILE(BUF, NB, u, SB, SA, SR, VM0, VM2, E0, E1, E2, E3, NE0, NE1)     \
  {                                                                          \
    /* P0: MFMA (nb0, ks0); prefetch bB(ks0)[E1], aY[0:3][E2|E3] */          \
    BAR; SB0;                                                                \
    if (E1) { bB[0] = LDB(BUF, 0, 2); bB[1] = LDB(BUF, 0, 3); }              \
    if ((E2) || (E3)) {                                                      \
      aY[0] = LDA(BUF, 1, 0); aY[1] = LDA(BUF, 1, 1);                        \
      aY[2] = LDA(BUF, 1, 2); aY[3] = LDA(BUF, 1, 3);                        \
    }                                                                        \
    if (E0) { PRIO1; MF8(aX, 0, bA[0]); MF8(aX, 1, bA[1]); PRIO0; }          \
    if (SB) { STB(NB, (u) + 1, 0, 0); STB(NB, (u) + 1, 1, 0); }              \
    VMW(VM0);                                                                \
    /* P1: MFMA (nb1, ks0); prefetch aY[4:7][E2|E3], bA(ks1)[E2] */          \
    BAR; SB0;                                                                \
    if ((E2) || (E3)) {                                                      \
      aY[4] = LDA(BUF, 1, 4); aY[5] = LDA(BUF, 1, 5);                        \
      aY[6] = LDA(BUF, 1, 6); aY[7] = LDA(BUF, 1, 7);                        \
    }                                                                        \
    if (E2) { bA[0] = LDB(BUF, 1, 0); bA[1] = LDB(BUF, 1, 1); }              \
    if (E1) { PRIO1; MF8(aX, 2, bB[0]); MF8(aX, 3, bB[1]); PRIO0; }          \
    if (SB) { STB(NB, (u) + 1, 0, 1); STB(NB, (u) + 1, 1, 1); }              \
    /* P2: MFMA (nb0, ks1); prefetch bB(ks1)[E3] */                          \
    BAR; SB0;                                                                \
    if (E3) { bB[0] = LDB(BUF, 1, 2); bB[1] = LDB(BUF, 1, 3); }              \
    if (E2) { PRIO1; MF8(aY, 0, bA[0]); MF8(aY, 1, bA[1]); PRIO0; }          \
    if (SA) { STA(BUF, (u) + 2, 0, 0); STA(BUF, (u) + 2, 1, 0); }            \
    VMW(VM2);                                                                \
    /* P3: MFMA (nb1, ks1); cross-tile prefetch aX[NE0|NE1], bA[NE0] */      \
    BAR; SB0;                                                                \
    if (SR) {                                                                \
      if ((NE0) || (NE1)) {                                                  \
        aX[0] = LDA(NB, 0, 0); aX[1] = LDA(NB, 0, 1);                        \
        aX[2] = LDA(NB, 0, 2); aX[3] = LDA(NB, 0, 3);                        \
        aX[4] = LDA(NB, 0, 4); aX[5] = LDA(NB, 0, 5);                        \
        aX[6] = LDA(NB, 0, 6); aX[7] = LDA(NB, 0, 7);                        \
      }                                                                      \
      if (NE0) { bA[0] = LDB(NB, 0, 0); bA[1] = LDB(NB, 0, 1); }             \
    }                                                                        \
    if (E3) { PRIO1; MF8(aY, 2, bB[0]); MF8(aY, 3, bB[1]); PRIO0; }          \
    if (SA) { STA(BUF, (u) + 2, 0, 1); STA(BUF, (u) + 2, 1, 1); }            \
  }

  f32x4 acc[8][4];
#pragma unroll
  for (int m = 0; m < 8; ++m)
#pragma unroll
    for (int n = 0; n < 4; ++n) acc[m][n] = (f32x4){0.f, 0.f, 0.f, 0.f};

  bf16x8 aX[8], aY[8], bA[2], bB[2];

  // prologue stages, ordered to reproduce the steady-state vmcnt FIFO window:
  // [A0ks0 A0ks1 B0ks0 B0ks1 | A1ks0 A1ks1]; vmcnt(4) -> A0,B0 landed.
  STA(0, 0, 0, 0); STA(0, 0, 1, 0); STA(0, 0, 0, 1); STA(0, 0, 1, 1);
  STB(0, 0, 0, 0); STB(0, 0, 1, 0); STB(0, 0, 0, 1); STB(0, 0, 1, 1);
  STA(1, 1, 0, 0); STA(1, 1, 1, 0); STA(1, 1, 0, 1); STA(1, 1, 1, 1);
  VMW(4);
  BAR; SB0;
  // preload tile-0 P0 operands (one-time; unconditional is harmless)
  aX[0] = LDA(0, 0, 0); aX[1] = LDA(0, 0, 1); aX[2] = LDA(0, 0, 2);
  aX[3] = LDA(0, 0, 3); aX[4] = LDA(0, 0, 4); aX[5] = LDA(0, 0, 5);
  aX[6] = LDA(0, 0, 6); aX[7] = LDA(0, 0, 7);
  bA[0] = LDB(0, 0, 0); bA[1] = LDB(0, 0, 1);

#pragma unroll 1
  for (int u = 0; u < NKT - 2; u += 2) {
    const int kc = 2 * u;
    TILE(0, 1, u, 1, 1, 1, 6, 4,
         BT(w00, w01, kc),     BT(w10, w11, kc),
         BT(w00, w01, kc + 1), BT(w10, w11, kc + 1),
         BT(w00, w01, kc + 2), BT(w10, w11, kc + 2));
    TILE(1, 0, u + 1, 1, 1, 1, 6, 4,
         BT(w00, w01, kc + 2), BT(w10, w11, kc + 2),
         BT(w00, w01, kc + 3), BT(w10, w11, kc + 3),
         BT(w00, w01, kc + 4), BT(w10, w11, kc + 4));
  }
  // peeled tails: tile 62 (kc 124,125; next bits 126), tile 63 (kc 126,127)
  TILE(0, 1, NKT - 2, 1, 0, 1, 6, 2,
       BT(w00, w01, 124), BT(w10, w11, 124),
       BT(w00, w01, 125), BT(w10, w11, 125),
       BT(w00, w01, 126), BT(w10, w11, 126));
  TILE(1, 0, NKT - 1, 0, 0, 0, 0, 0,
       BT(w00, w01, 126), BT(w10, w11, 126),
       BT(w00, w01, 127), BT(w10, w11, 127), 0, 0);

  // epilogue: C/D layout col=lane&15 (=r), row=(lane>>4)*4+j (=g0*4+j)
  const int orow = rowM + wr * 128;
  const int ocol = colN + wc * 64;
#pragma unroll
  for (int n = 0; n < 4; ++n) {
    int col = ocol + n * 16 + r;
    float bz = bias[col];
#pragma unroll
    for (int m = 0; m < 8; ++m) {
      int row0 = orow + m * 16 + g0 * 4;
#pragma unroll
      for (int j = 0; j < 4; ++j)
        out[(size_t)(row0 + j) * N_DIM + col] = acc[m][n][j] + bz;
    }
  }
#undef TILE
#undef GLL
#undef STA
#undef STB
#undef LDA
#undef LDB
#undef MF8
#undef BAR
#undef SB0
#undef PRIO1
#undef PRIO0
#undef VMW
#undef VMW_
#undef BT
}

// ---------------- fallback (ws too small): naive fp32 ----------------
__global__ __launch_bounds__(256) void k_naive(const float* __restrict__ A,
                                               const float* __restrict__ W,
                                               const float* __restrict__ bias,
                                               const int* __restrict__ bm,
                                               float* __restrict__ out) {
  int col = blockIdx.x * 16 + (threadIdx.x & 15);
  int row = blockIdx.y * 16 + (threadIdx.x >> 4);
  float s = 0.f;
  for (int kb = 0; kb < K_DIM / 32; ++kb) {
    if (bm[(col >> 5) * NW + kb]) {
      int kbase = kb * 32;
#pragma unroll 8
      for (int k = 0; k < 32; ++k)
        s += A[(size_t)row * K_DIM + kbase + k] * W[(size_t)col * K_DIM + kbase + k];
    }
  }
  out[(size_t)row * N_DIM + col] = s + bias[col];
}

extern "C" void kernel_launch(void* const* d_in, const int* in_sizes, int n_in,
                              void* d_out, int out_size, void* d_ws, size_t ws_size,
                              hipStream_t stream) {
  const float* data = (const float*)d_in[0];
  const float* weight = (const float*)d_in[1];
  const float* bias = (const float*)d_in[2];
  const int* mask = (const int*)d_in[3];
  const float* conv_bias = (const float*)d_in[4];
  float* out = (float*)d_out;

  int* bm = (int*)d_ws;
  const size_t off_a = 65536;
  const size_t off_b = off_a + (size_t)M_DIM * K_DIM * 2;
  const size_t needed = off_b + (size_t)N_DIM * K_DIM * 2;

  k_block_mask<<<dim3(NW, NH), 256, 0, stream>>>(mask, conv_bias, bm);

  if (ws_size >= needed) {
    short* Abf = (short*)((char*)d_ws + off_a);
    short* Wbf = (short*)((char*)d_ws + off_b);
    k_cvt_data<<<dim3((M_DIM * (K_DIM / 4)) / 256), 256, 0, stream>>>(data, Abf);
    k_cvt_weight<<<dim3((N_DIM * (K_DIM / 4)) / 256), 256, 0, stream>>>(weight, bm, Wbf);
    k_gemm256<<<dim3(256), 512, 0, stream>>>(Abf, Wbf, bias, bm, out);
  } else {
    k_naive<<<dim3(N_DIM / 16, M_DIM / 16), 256, 0, stream>>>(data, weight, bias, bm, out);
  }
}